// Round 6
// baseline (412.950 us; speedup 1.0000x reference)
//
#include <hip/hip_runtime.h>
#include <hip/hip_bf16.h>

typedef unsigned short u16;
typedef __attribute__((ext_vector_type(8))) __bf16 bf16x8;
typedef __attribute__((ext_vector_type(4))) float f32x4;
typedef __attribute__((ext_vector_type(2))) unsigned int u32x2;

#define DEV __device__ __forceinline__

DEV u16 f2bf(float f) {
  union { float f; unsigned int u; } v; v.f = f;
  unsigned int x = v.u;
  return (u16)((x + 0x7fffu + ((x >> 16) & 1u)) >> 16);  // RNE
}

DEV void gload_lds16(const u16* g, u16* l) {
  __builtin_amdgcn_global_load_lds(
      (__attribute__((address_space(1))) void*)(g),
      (__attribute__((address_space(3))) void*)(l), 16, 0, 0);
}

// ---------------- LayerNorm + cast to bf16 ----------------
template <int NV>
__global__ __launch_bounds__(256) void ln_cast(const float* __restrict__ x,
                                               const float* __restrict__ g,
                                               const float* __restrict__ b,
                                               u16* __restrict__ out, int C) {
  int row = blockIdx.x;
  int tid = threadIdx.x;
  const float4* xr = (const float4*)(x + (size_t)row * C);
  float4 v[NV];
  float s = 0.f, ss = 0.f;
#pragma unroll
  for (int i = 0; i < NV; i++) {
    v[i] = xr[tid + i * 256];
    s += v[i].x + v[i].y + v[i].z + v[i].w;
    ss += v[i].x * v[i].x + v[i].y * v[i].y + v[i].z * v[i].z + v[i].w * v[i].w;
  }
#pragma unroll
  for (int off = 32; off > 0; off >>= 1) {
    s += __shfl_down(s, off);
    ss += __shfl_down(ss, off);
  }
  __shared__ float red[8];
  int wv = tid >> 6;
  if ((tid & 63) == 0) { red[wv] = s; red[4 + wv] = ss; }
  __syncthreads();
  float S = red[0] + red[1] + red[2] + red[3];
  float SS = red[4] + red[5] + red[6] + red[7];
  float mu = S / C;
  float rstd = rsqrtf(SS / C - mu * mu + 1e-5f);
  const float4* gr = (const float4*)g;
  const float4* br = (const float4*)b;
  ushort4* orow = (ushort4*)(out + (size_t)row * C);
#pragma unroll
  for (int i = 0; i < NV; i++) {
    int gi = tid + i * 256;
    float4 gv = gr[gi], bv = br[gi];
    ushort4 o;
    o.x = f2bf((v[i].x - mu) * rstd * gv.x + bv.x);
    o.y = f2bf((v[i].y - mu) * rstd * gv.y + bv.y);
    o.z = f2bf((v[i].z - mu) * rstd * gv.z + bv.z);
    o.w = f2bf((v[i].w - mu) * rstd * gv.w + bv.w);
    orow[gi] = o;
  }
}

// ---------------- transpose + cast f32 -> bf16 ----------------
__global__ __launch_bounds__(256) void transpose_cast(const float* __restrict__ in,
                                                      u16* __restrict__ out,
                                                      int K, int N) {
  __shared__ float t[32][33];
  int tx = threadIdx.x & 31, ty = threadIdx.x >> 5;
  int n0 = blockIdx.x * 32, k0 = blockIdx.y * 32;
#pragma unroll
  for (int i = 0; i < 32; i += 8)
    t[ty + i][tx] = in[(size_t)(k0 + ty + i) * N + n0 + tx];
  __syncthreads();
#pragma unroll
  for (int i = 0; i < 32; i += 8)
    out[(size_t)(n0 + ty + i) * K + k0 + tx] = f2bf(t[tx][ty + i]);
}

// ---------------- build VT[bh][128][1024] from KV ----------------
__global__ __launch_bounds__(256) void build_vt(const u16* __restrict__ KV,
                                                u16* __restrict__ VT) {
  __shared__ u16 t[32][33];
  int bh = blockIdx.z, b = bh >> 4, h = bh & 15;
  int d0 = blockIdx.x * 32, s0 = blockIdx.y * 32;
  int tx = threadIdx.x & 31, ty = threadIdx.x >> 5;
  const u16* src = KV + (size_t)(b * 1024) * 4096 + 2048 + h * 128;
#pragma unroll
  for (int i = 0; i < 32; i += 8)
    t[ty + i][tx] = src[(size_t)(s0 + ty + i) * 4096 + d0 + tx];
  __syncthreads();
  u16* dst = VT + (size_t)bh * (128 * 1024);
#pragma unroll
  for (int i = 0; i < 32; i += 8)
    dst[(size_t)(d0 + ty + i) * 1024 + s0 + tx] = t[tx][ty + i];
}

// ---------------- GEMM: C[M,N] = oscale * A[M,K] * BT[N,K]^T ----------------
DEV void storeC(u16* C, size_t idx, float v) { C[idx] = f2bf(v); }
DEV void storeC(float* C, size_t idx, float v) { C[idx] = v; }

template <typename OutT>
__global__ __launch_bounds__(256) void gemm_bt(const u16* __restrict__ A,
                                               const u16* __restrict__ BT,
                                               OutT* __restrict__ C,
                                               int M, int N, int K, float oscale) {
  constexpr int BK = 32;
  __shared__ __attribute__((aligned(16))) u16 As[128 * BK];
  __shared__ __attribute__((aligned(16))) u16 Bs[128 * BK];
  // XCD-aware swizzle (grid % 8 == 0 for all our launches -> bijective):
  // hw block b runs on XCD b%8; give each XCD a contiguous chunk of orig ids.
  int nwg = gridDim.x;
  int cpx = nwg >> 3;
  int bid = (blockIdx.x & 7) * cpx + (blockIdx.x >> 3);
  int tilesN = N >> 7;
  int bm = (bid / tilesN) << 7;
  int bn = (bid % tilesN) << 7;
  int tid = threadIdx.x;
  int lane = tid & 63, wave = tid >> 6;
  int wm = (wave >> 1) << 6, wn = (wave & 1) << 6;
  int srow = wave * 16 + (lane >> 2);
  int scol = (lane & 3) * 8;
  int fr = lane & 15, fk = (lane >> 4) * 8;
  const u16* Ab = A + (size_t)bm * K;
  const u16* Bb = BT + (size_t)bn * K;
  f32x4 acc[4][4] = {};

  for (int kt = 0; kt < K; kt += BK) {
#pragma unroll
    for (int j = 0; j < 2; j++) {
      gload_lds16(Ab + (size_t)(j * 64 + srow) * K + kt + scol,
                  &As[(j * 64 + wave * 16) * BK]);
      gload_lds16(Bb + (size_t)(j * 64 + srow) * K + kt + scol,
                  &Bs[(j * 64 + wave * 16) * BK]);
    }
    __syncthreads();
    bf16x8 af[4], bfr[4];
#pragma unroll
    for (int m = 0; m < 4; m++)
      af[m] = *(const bf16x8*)&As[(wm + m * 16 + fr) * BK + fk];
#pragma unroll
    for (int n = 0; n < 4; n++)
      bfr[n] = *(const bf16x8*)&Bs[(wn + n * 16 + fr) * BK + fk];
#pragma unroll
    for (int m = 0; m < 4; m++)
#pragma unroll
      for (int n = 0; n < 4; n++)
        acc[m][n] = __builtin_amdgcn_mfma_f32_16x16x32_bf16(af[m], bfr[n], acc[m][n], 0, 0, 0);
    __syncthreads();
  }

#pragma unroll
  for (int m = 0; m < 4; m++) {
    int rbase = bm + wm + m * 16 + ((lane >> 4) << 2);
#pragma unroll
    for (int n = 0; n < 4; n++) {
      int col = bn + wn + n * 16 + fr;
#pragma unroll
      for (int r = 0; r < 4; r++)
        storeC(C, (size_t)(rbase + r) * N + col, acc[m][n][r] * oscale);
    }
  }
}

// ---------------- fused flash attention (v5) ----------------
// 4 waves x 16 q-rows = 64 q-rows/block, grid = B*H*(SQ/64) = 1024 blocks.
// 3 blocks/CU (LDS 41KB, VGPR<=170 via launch_bounds(256,3)) -> 12 waves/CU.
// Swapped QK^T (lane owns one q-row's 16 kv values), in-lane softmax,
// defer-max rescale (THR=8), K LDS-staged dbuf w/ swizzled source,
// V prefetched to regs.
__global__ __launch_bounds__(256, 3) void attn_kernel(const u16* __restrict__ Q,
                                                      const u16* __restrict__ KV,
                                                      const u16* __restrict__ VT,
                                                      u16* __restrict__ O) {
  const int SQ = 2048, SKV = 1024;
  const int NCHUNK = SKV / 64;
  int qt = blockIdx.x & 31, bh = blockIdx.x >> 5;
  int b = bh >> 4, h = bh & 15;
  int wave = threadIdx.x >> 6, lane = threadIdx.x & 63;
  int q0 = qt * 64 + wave * 16;
  int fr = lane & 15, g = lane >> 4, fkb = g * 8;

  __shared__ __attribute__((aligned(16))) u16 Ks[2][64 * 128];
  __shared__ __attribute__((aligned(16))) u16 Pb[4][16 * 72];  // row stride 72 (144B)
  u16* P = &Pb[wave][0];

  bf16x8 qf[4];
  {
    const u16* Qbase = Q + (size_t)(b * SQ + q0 + fr) * 2048 + h * 128;
#pragma unroll
    for (int kd = 0; kd < 4; kd++)
      qf[kd] = *(const bf16x8*)(Qbase + kd * 32 + fkb);
  }

  const u16* Kb = KV + (size_t)(b * SKV) * 4096 + h * 128;
  const u16* Vt = VT + (size_t)bh * (128 * 1024);

  auto stage = [&](int c, int buf) {
#pragma unroll
    for (int j = 0; j < 4; j++) {
      int r = wave * 16 + j * 4 + g;
      int gb = (lane & 15) ^ (r & 7);
      gload_lds16(Kb + (size_t)(c * 64 + r) * 4096 + gb * 8,
                  &Ks[buf][(wave * 16 + j * 4) * 128]);
    }
  };

  f32x4 o[8] = {};
  float mrun = -1e30f, lrun = 0.f;

  stage(0, 0);
  __syncthreads();
  int buf = 0;

  for (int c = 0; c < NCHUNK; c++) {
    if (c + 1 < NCHUNK) stage(c + 1, buf ^ 1);

    // swapped QK^T: acc[kv_t][r] = S[q = fr][kv = kv_t*16 + g*4 + r]
    f32x4 acc[4] = {};
#pragma unroll
    for (int kv_t = 0; kv_t < 4; kv_t++) {
      int row = kv_t * 16 + fr;
#pragma unroll
      for (int kd = 0; kd < 4; kd++) {
        int pb = (kd * 4 + g) ^ (fr & 7);
        bf16x8 kf = *(const bf16x8*)&Ks[buf][row * 128 + pb * 8];
        acc[kv_t] = __builtin_amdgcn_mfma_f32_16x16x32_bf16(kf, qf[kd], acc[kv_t], 0, 0, 0);
      }
    }

    // prefetch V (latency hides under softmax)
    bf16x8 vf0[8], vf1[8];
#pragma unroll
    for (int nn = 0; nn < 8; nn++) {
      const u16* vrow = Vt + (size_t)(nn * 16 + fr) * 1024 + c * 64 + fkb;
      vf0[nn] = *(const bf16x8*)(vrow);
      vf1[nn] = *(const bf16x8*)(vrow + 32);
    }

    // in-lane softmax for q = fr (16 kv values per lane)
    float pm = fmaxf(fmaxf(fmaxf(acc[0][0], acc[0][1]), fmaxf(acc[0][2], acc[0][3])),
                     fmaxf(fmaxf(acc[1][0], acc[1][1]), fmaxf(acc[1][2], acc[1][3])));
    pm = fmaxf(pm, fmaxf(fmaxf(fmaxf(acc[2][0], acc[2][1]), fmaxf(acc[2][2], acc[2][3])),
                         fmaxf(fmaxf(acc[3][0], acc[3][1]), fmaxf(acc[3][2], acc[3][3]))));
    pm = fmaxf(pm, __shfl_xor(pm, 16));
    pm = fmaxf(pm, __shfl_xor(pm, 32));

    // defer-max: only rescale when the new tile max exceeds mrun + 8
    if (!__all(pm <= mrun + 8.f)) {
      float mn = fmaxf(mrun, pm);
      float corr = __expf(mrun - mn);
      mrun = mn;
      lrun *= corr;
      float corr_o[4];
#pragma unroll
      for (int r = 0; r < 4; r++) corr_o[r] = __shfl(corr, g * 4 + r);
#pragma unroll
      for (int nn = 0; nn < 8; nn++) {
        o[nn][0] *= corr_o[0]; o[nn][1] *= corr_o[1];
        o[nn][2] *= corr_o[2]; o[nn][3] *= corr_o[3];
      }
    }

    float psum = 0.f;
#pragma unroll
    for (int kv_t = 0; kv_t < 4; kv_t++) {
      float p0 = __expf(acc[kv_t][0] - mrun);
      float p1 = __expf(acc[kv_t][1] - mrun);
      float p2 = __expf(acc[kv_t][2] - mrun);
      float p3 = __expf(acc[kv_t][3] - mrun);
      psum += (p0 + p1) + (p2 + p3);
      union { __hip_bfloat162 h; unsigned int u; } lo, hi;
      lo.h = __float22bfloat162_rn(make_float2(p0, p1));
      hi.h = __float22bfloat162_rn(make_float2(p2, p3));
      u32x2 w = {lo.u, hi.u};
      *(u32x2*)&P[fr * 72 + kv_t * 16 + g * 4] = w;
    }
    lrun += psum;

    // PV (P per-wave in LDS; drain ds_writes before reading)
    asm volatile("s_waitcnt lgkmcnt(0)" ::: "memory");
    {
      bf16x8 pa0 = *(const bf16x8*)&P[fr * 72 + fkb];
#pragma unroll
      for (int nn = 0; nn < 8; nn++)
        o[nn] = __builtin_amdgcn_mfma_f32_16x16x32_bf16(pa0, vf0[nn], o[nn], 0, 0, 0);
      bf16x8 pa1 = *(const bf16x8*)&P[fr * 72 + 32 + fkb];
#pragma unroll
      for (int nn = 0; nn < 8; nn++)
        o[nn] = __builtin_amdgcn_mfma_f32_16x16x32_bf16(pa1, vf1[nn], o[nn], 0, 0, 0);
    }

    __syncthreads();
    buf ^= 1;
  }

  // final l: reduce across the 4 g-copies, redistribute to o layout, store
  {
    float lt = lrun;
    lt += __shfl_xor(lt, 16);
    lt += __shfl_xor(lt, 32);
    float linv_o[4];
#pragma unroll
    for (int r = 0; r < 4; r++) linv_o[r] = 1.0f / __shfl(lt, g * 4 + r);
#pragma unroll
    for (int r = 0; r < 4; r++) {
      int row = b * SQ + q0 + g * 4 + r;
      u16* Or = O + (size_t)row * 2048 + h * 128;
#pragma unroll
      for (int nn = 0; nn < 8; nn++) Or[nn * 16 + fr] = f2bf(o[nn][r] * linv_o[r]);
    }
  }
}

// ---------------- launch ----------------
extern "C" void kernel_launch(void* const* d_in, const int* in_sizes, int n_in,
                              void* d_out, int out_size, void* d_ws, size_t ws_size,
                              hipStream_t stream) {
  const float* image_embeds  = (const float*)d_in[0];  // [2,1024,2048]
  const float* hidden_states = (const float*)d_in[1];  // [2,2048,3072]
  const float* Wq   = (const float*)d_in[2];           // [3072,2048]
  const float* Wkv  = (const float*)d_in[3];           // [2048,4096]
  const float* Wout = (const float*)d_in[4];           // [2048,3072]
  const float* ln1_g = (const float*)d_in[5];
  const float* ln1_b = (const float*)d_in[6];
  const float* ln2_g = (const float*)d_in[7];
  const float* ln2_b = (const float*)d_in[8];
  float* out = (float*)d_out;

  char* ws = (char*)d_ws;
  size_t off = 0;
  auto alloc = [&](size_t bytes) {
    void* p = ws + off;
    off += (bytes + 255) & ~(size_t)255;
    return p;
  };
  u16* Xq   = (u16*)alloc((size_t)4096 * 3072 * 2);  // LN(hidden) bf16; reused as AO
  u16* Xkv  = (u16*)alloc((size_t)2048 * 2048 * 2);  // LN(image) bf16
  u16* WqT  = (u16*)alloc((size_t)2048 * 3072 * 2);  // Wq^T bf16; reused as VT
  u16* WkvT = (u16*)alloc((size_t)4096 * 2048 * 2);  // Wkv^T bf16
  u16* WoT  = (u16*)alloc((size_t)3072 * 2048 * 2);  // Wout^T bf16
  u16* Qb   = (u16*)alloc((size_t)4096 * 2048 * 2);  // q bf16 (pre-scaled)
  u16* KVb  = (u16*)alloc((size_t)2048 * 4096 * 2);  // kv bf16
  u16* VTb  = WqT;   // alias: WqT dead after q-gemm
  u16* AO   = Xq;    // alias: Xq dead after q-gemm

  const float qscale = 0.08838834764831845f;  // 1/sqrt(128)

  ln_cast<3><<<4096, 256, 0, stream>>>(hidden_states, ln2_g, ln2_b, Xq, 3072);
  ln_cast<2><<<2048, 256, 0, stream>>>(image_embeds, ln1_g, ln1_b, Xkv, 2048);
  transpose_cast<<<dim3(2048 / 32, 3072 / 32), 256, 0, stream>>>(Wq, WqT, 3072, 2048);
  transpose_cast<<<dim3(4096 / 32, 2048 / 32), 256, 0, stream>>>(Wkv, WkvT, 2048, 4096);
  transpose_cast<<<dim3(3072 / 32, 2048 / 32), 256, 0, stream>>>(Wout, WoT, 2048, 3072);

  gemm_bt<u16><<<(4096 / 128) * (2048 / 128), 256, 0, stream>>>(Xq, WqT, Qb, 4096, 2048, 3072, qscale);
  gemm_bt<u16><<<(2048 / 128) * (4096 / 128), 256, 0, stream>>>(Xkv, WkvT, KVb, 2048, 4096, 2048, 1.0f);

  build_vt<<<dim3(4, 32, 32), 256, 0, stream>>>(KVb, VTb);
  attn_kernel<<<1024, 256, 0, stream>>>(Qb, KVb, VTb, AO);

  gemm_bt<float><<<(4096 / 128) * (3072 / 128), 256, 0, stream>>>(AO, WoT, out, 4096, 3072, 2048, 1.0f);
}

// Round 7
// 302.416 us; speedup vs baseline: 1.3655x; 1.3655x over previous
//
#include <hip/hip_runtime.h>
#include <hip/hip_bf16.h>

typedef unsigned short u16;
typedef __attribute__((ext_vector_type(8))) __bf16 bf16x8;
typedef __attribute__((ext_vector_type(4))) float f32x4;
typedef __attribute__((ext_vector_type(2))) unsigned int u32x2;

#define DEV __device__ __forceinline__

DEV u16 f2bf(float f) {
  union { float f; unsigned int u; } v; v.f = f;
  unsigned int x = v.u;
  return (u16)((x + 0x7fffu + ((x >> 16) & 1u)) >> 16);  // RNE
}

DEV void gload_lds16(const u16* g, u16* l) {
  __builtin_amdgcn_global_load_lds(
      (__attribute__((address_space(1))) void*)(g),
      (__attribute__((address_space(3))) void*)(l), 16, 0, 0);
}

// ---------------- LayerNorm + cast to bf16 ----------------
template <int NV>
__global__ __launch_bounds__(256) void ln_cast(const float* __restrict__ x,
                                               const float* __restrict__ g,
                                               const float* __restrict__ b,
                                               u16* __restrict__ out, int C) {
  int row = blockIdx.x;
  int tid = threadIdx.x;
  const float4* xr = (const float4*)(x + (size_t)row * C);
  float4 v[NV];
  float s = 0.f, ss = 0.f;
#pragma unroll
  for (int i = 0; i < NV; i++) {
    v[i] = xr[tid + i * 256];
    s += v[i].x + v[i].y + v[i].z + v[i].w;
    ss += v[i].x * v[i].x + v[i].y * v[i].y + v[i].z * v[i].z + v[i].w * v[i].w;
  }
#pragma unroll
  for (int off = 32; off > 0; off >>= 1) {
    s += __shfl_down(s, off);
    ss += __shfl_down(ss, off);
  }
  __shared__ float red[8];
  int wv = tid >> 6;
  if ((tid & 63) == 0) { red[wv] = s; red[4 + wv] = ss; }
  __syncthreads();
  float S = red[0] + red[1] + red[2] + red[3];
  float SS = red[4] + red[5] + red[6] + red[7];
  float mu = S / C;
  float rstd = rsqrtf(SS / C - mu * mu + 1e-5f);
  const float4* gr = (const float4*)g;
  const float4* br = (const float4*)b;
  ushort4* orow = (ushort4*)(out + (size_t)row * C);
#pragma unroll
  for (int i = 0; i < NV; i++) {
    int gi = tid + i * 256;
    float4 gv = gr[gi], bv = br[gi];
    ushort4 o;
    o.x = f2bf((v[i].x - mu) * rstd * gv.x + bv.x);
    o.y = f2bf((v[i].y - mu) * rstd * gv.y + bv.y);
    o.z = f2bf((v[i].z - mu) * rstd * gv.z + bv.z);
    o.w = f2bf((v[i].w - mu) * rstd * gv.w + bv.w);
    orow[gi] = o;
  }
}

// ---------------- transpose + cast f32 -> bf16 ----------------
__global__ __launch_bounds__(256) void transpose_cast(const float* __restrict__ in,
                                                      u16* __restrict__ out,
                                                      int K, int N) {
  __shared__ float t[32][33];
  int tx = threadIdx.x & 31, ty = threadIdx.x >> 5;
  int n0 = blockIdx.x * 32, k0 = blockIdx.y * 32;
#pragma unroll
  for (int i = 0; i < 32; i += 8)
    t[ty + i][tx] = in[(size_t)(k0 + ty + i) * N + n0 + tx];
  __syncthreads();
#pragma unroll
  for (int i = 0; i < 32; i += 8)
    out[(size_t)(n0 + ty + i) * K + k0 + tx] = f2bf(t[tx][ty + i]);
}

// ---------------- build VT[bh][128][1024] from KV ----------------
__global__ __launch_bounds__(256) void build_vt(const u16* __restrict__ KV,
                                                u16* __restrict__ VT) {
  __shared__ u16 t[32][33];
  int bh = blockIdx.z, b = bh >> 4, h = bh & 15;
  int d0 = blockIdx.x * 32, s0 = blockIdx.y * 32;
  int tx = threadIdx.x & 31, ty = threadIdx.x >> 5;
  const u16* src = KV + (size_t)(b * 1024) * 4096 + 2048 + h * 128;
#pragma unroll
  for (int i = 0; i < 32; i += 8)
    t[ty + i][tx] = src[(size_t)(s0 + ty + i) * 4096 + d0 + tx];
  __syncthreads();
  u16* dst = VT + (size_t)bh * (128 * 1024);
#pragma unroll
  for (int i = 0; i < 32; i += 8)
    dst[(size_t)(d0 + ty + i) * 1024 + s0 + tx] = t[tx][ty + i];
}

DEV void storeC(u16* C, size_t idx, float v) { C[idx] = f2bf(v); }
DEV void storeC(float* C, size_t idx, float v) { C[idx] = v; }

#define MFMA16(a, b, c) __builtin_amdgcn_mfma_f32_16x16x32_bf16((a), (b), (c), 0, 0, 0)

// ---------------- 256x256 8-phase pipelined GEMM ----------------
// C[M,N] = oscale * A[M,K] * BT[N,K]^T, bf16 in, fp32 acc.
// 512 threads (8 waves = 2Mx4N), per-wave 128x64 out (acc[8][4]).
// BK=64, 2 LDS buffers (128 KB). Per K-tile: 4 phases of 16 MFMA,
// quadrants (mh,nh) with register-held operand reuse so LDS region
// last-reads are: A0@P1, B0@P1, B1@P2, A1@P3.
// Stage stream (1 unit = 16KB = 2 gload_lds16/wave, per phase):
//   P1: A1(X+1)->buf^1 | P2: A0(X+2)->buf | P3: B0(X+2)->buf | P4: B1(X+2)->buf
// Every overwrite lands >=1 phase after the region's last read (barriers).
// vmcnt(6) once per tile (3 units in flight); vmcnt(0) for the last 2 tiles.
// LDS XOR-swizzle slot^= (row&7) applied on stage source and ds_read.
// Optionally runs 2 problems in one launch (blocks < nblk0 -> problem 0).
template <typename OutT>
__global__ __launch_bounds__(512, 2) void gemm8(
    const u16* __restrict__ Aa, const u16* __restrict__ Ba, OutT* __restrict__ Ca,
    int Na, int Ka, float osa,
    const u16* __restrict__ Ab2, const u16* __restrict__ Bb2, OutT* __restrict__ Cb2,
    int Nb, int Kb, float osb, int nblk0) {
  __shared__ __attribute__((aligned(16))) u16 Alds[2][256 * 64];
  __shared__ __attribute__((aligned(16))) u16 Blds[2][256 * 64];

  int nwg = gridDim.x;
  int bid = ((int)blockIdx.x & 7) * (nwg >> 3) + ((int)blockIdx.x >> 3);

  const u16* A; const u16* B; OutT* C; int N, K; float oscale;
  if (bid < nblk0) { A = Aa; B = Ba; C = Ca; N = Na; K = Ka; oscale = osa; }
  else { bid -= nblk0; A = Ab2; B = Bb2; C = Cb2; N = Nb; K = Kb; oscale = osb; }

  int tilesN = N >> 8;
  int bm = (bid / tilesN) << 8;
  int bn = (bid % tilesN) << 8;
  int tid = threadIdx.x, lane = tid & 63, w = tid >> 6;
  int wr = w >> 2, wc = w & 3;
  int fr = lane & 15, g = lane >> 4;
  const u16* Abase = A + (size_t)bm * K;
  const u16* Bbase = B + (size_t)bn * K;

  // per-lane staging source offsets (swizzled: col slot ^= row&7)
  int lrow = lane >> 3;                       // 0..7 within 8-row block
  int lcol = (((lane & 7) ^ lrow) << 3);      // element col within 64

  // stage one 16KB unit: 2 x 1KB (8-row) blocks per wave
  auto stageA = [&](int kt, int unit, int bufb) {
#pragma unroll
    for (int j = 0; j < 2; j++) {
      int bi = w * 2 + j;                                   // 0..15
      int r0 = ((bi >> 3) << 7) + (unit << 6) + ((bi & 7) << 3);
      gload_lds16(Abase + (size_t)(r0 + lrow) * K + kt + lcol,
                  &Alds[bufb][r0 * 64]);
    }
  };
  auto stageB = [&](int kt, int unit, int bufb) {
#pragma unroll
    for (int j = 0; j < 2; j++) {
      int bi = w * 2 + j;
      int r0 = ((bi >> 2) << 6) + (unit << 5) + ((bi & 3) << 3);
      gload_lds16(Bbase + (size_t)(r0 + lrow) * K + kt + lcol,
                  &Blds[bufb][r0 * 64]);
    }
  };
  auto rdA = [&](int bufb, int m, int kk) {
    int row = (wr << 7) + m * 16 + fr;
    int slot = (kk * 4 + g) ^ (fr & 7);
    return *(const bf16x8*)&Alds[bufb][row * 64 + slot * 8];
  };
  auto rdB = [&](int bufb, int n, int kk) {
    int row = (wc << 6) + n * 16 + fr;
    int slot = (kk * 4 + g) ^ (fr & 7);
    return *(const bf16x8*)&Blds[bufb][row * 64 + slot * 8];
  };

  f32x4 acc[8][4] = {};
  const int NT = K >> 6;

  // prologue: units in stream order (7 units, tile0 + A0/B0/B1 of tile1)
  stageA(0, 0, 0); stageB(0, 0, 0); stageB(0, 1, 0); stageA(0, 1, 0);
  stageA(64, 0, 1); stageB(64, 0, 1); stageB(64, 1, 1);
  asm volatile("s_waitcnt vmcnt(6)" ::: "memory");   // tile 0 landed
  __builtin_amdgcn_sched_barrier(0);
  __builtin_amdgcn_s_barrier();

  bf16x8 af[4][2], bf0[2][2], bf1[2][2];
  for (int X = 0; X < NT; ++X) {
    int cur = X & 1, nxt = cur ^ 1;

    // ---- P1: quadrant (mh0, nh0); read A0 + B0; stage A1(X+1) ----
#pragma unroll
    for (int m = 0; m < 4; m++) { af[m][0] = rdA(cur, m, 0); af[m][1] = rdA(cur, m, 1); }
#pragma unroll
    for (int n = 0; n < 2; n++) { bf0[n][0] = rdB(cur, n, 0); bf0[n][1] = rdB(cur, n, 1); }
    if (X + 1 < NT) stageA((X + 1) << 6, 1, nxt);
    __builtin_amdgcn_s_barrier();
    __builtin_amdgcn_s_setprio(1);
#pragma unroll
    for (int m = 0; m < 4; m++)
#pragma unroll
      for (int n = 0; n < 2; n++) {
        acc[m][n] = MFMA16(af[m][0], bf0[n][0], acc[m][n]);
        acc[m][n] = MFMA16(af[m][1], bf0[n][1], acc[m][n]);
      }
    __builtin_amdgcn_s_setprio(0);
    __builtin_amdgcn_s_barrier();

    // ---- P2: (mh0, nh1); read B1; reuse af; stage A0(X+2) ----
#pragma unroll
    for (int n = 0; n < 2; n++) { bf1[n][0] = rdB(cur, n + 2, 0); bf1[n][1] = rdB(cur, n + 2, 1); }
    if (X + 2 < NT) stageA((X + 2) << 6, 0, cur);
    __builtin_amdgcn_s_barrier();
    __builtin_amdgcn_s_setprio(1);
#pragma unroll
    for (int m = 0; m < 4; m++)
#pragma unroll
      for (int n = 0; n < 2; n++) {
        acc[m][n + 2] = MFMA16(af[m][0], bf1[n][0], acc[m][n + 2]);
        acc[m][n + 2] = MFMA16(af[m][1], bf1[n][1], acc[m][n + 2]);
      }
    __builtin_amdgcn_s_setprio(0);
    __builtin_amdgcn_s_barrier();

    // ---- P3: (mh1, nh0); read A1; reuse bf0; stage B0(X+2) ----
#pragma unroll
    for (int m = 0; m < 4; m++) { af[m][0] = rdA(cur, m + 4, 0); af[m][1] = rdA(cur, m + 4, 1); }
    if (X + 2 < NT) stageB((X + 2) << 6, 0, cur);
    __builtin_amdgcn_s_barrier();
    __builtin_amdgcn_s_setprio(1);
#pragma unroll
    for (int m = 0; m < 4; m++)
#pragma unroll
      for (int n = 0; n < 2; n++) {
        acc[m + 4][n] = MFMA16(af[m][0], bf0[n][0], acc[m + 4][n]);
        acc[m + 4][n] = MFMA16(af[m][1], bf0[n][1], acc[m + 4][n]);
      }
    __builtin_amdgcn_s_setprio(0);
    __builtin_amdgcn_s_barrier();

    // ---- P4: (mh1, nh1); no reads (reuse af + bf1); stage B1(X+2) ----
    if (X + 2 < NT) stageB((X + 2) << 6, 1, cur);
    __builtin_amdgcn_s_barrier();
    __builtin_amdgcn_s_setprio(1);
#pragma unroll
    for (int m = 0; m < 4; m++)
#pragma unroll
      for (int n = 0; n < 2; n++) {
        acc[m + 4][n + 2] = MFMA16(af[m][0], bf1[n][0], acc[m + 4][n + 2]);
        acc[m + 4][n + 2] = MFMA16(af[m][1], bf1[n][1], acc[m + 4][n + 2]);
      }
    __builtin_amdgcn_s_setprio(0);
    if (X + 2 < NT) {
      asm volatile("s_waitcnt vmcnt(6)" ::: "memory");  // tile X+1 landed
    } else {
      asm volatile("s_waitcnt vmcnt(0)" ::: "memory");  // drain
    }
    __builtin_amdgcn_sched_barrier(0);
    __builtin_amdgcn_s_barrier();
  }

  // epilogue
#pragma unroll
  for (int m = 0; m < 8; m++) {
    int rbase = bm + (wr << 7) + m * 16 + g * 4;
#pragma unroll
    for (int n = 0; n < 4; n++) {
      int col = bn + (wc << 6) + n * 16 + fr;
#pragma unroll
      for (int r = 0; r < 4; r++)
        storeC(C, (size_t)(rbase + r) * N + col, acc[m][n][r] * oscale);
    }
  }
}

// ---------------- fused flash attention (R4 proven version) ----------------
// 4 waves x 32 q-rows (2 q-groups of 16) = 128 q-rows per block, grid 512.
__global__ __launch_bounds__(256) void attn_kernel(const u16* __restrict__ Q,
                                                   const u16* __restrict__ KV,
                                                   const u16* __restrict__ VT,
                                                   u16* __restrict__ O) {
  const int SQ = 2048, SKV = 1024;
  const int NCHUNK = SKV / 64;
  int qt = blockIdx.x & 15, bh = blockIdx.x >> 4;
  int b = bh >> 4, h = bh & 15;
  int wave = threadIdx.x >> 6, lane = threadIdx.x & 63;
  int q0 = qt * 128 + wave * 32;
  int fr = lane & 15, g = lane >> 4, fkb = g * 8;

  __shared__ __attribute__((aligned(16))) u16 Ks[2][64 * 128];
  __shared__ __attribute__((aligned(16))) u16 Pb[4][32 * 72];
  u16* P = &Pb[wave][0];

  bf16x8 qf[2][4];
#pragma unroll
  for (int gq = 0; gq < 2; gq++) {
    const u16* Qbase = Q + (size_t)(b * SQ + q0 + gq * 16 + fr) * 2048 + h * 128;
#pragma unroll
    for (int kd = 0; kd < 4; kd++)
      qf[gq][kd] = *(const bf16x8*)(Qbase + kd * 32 + fkb);
  }

  const u16* Kb = KV + (size_t)(b * SKV) * 4096 + h * 128;
  const u16* Vt = VT + (size_t)bh * (128 * 1024);

  auto stage = [&](int c, int buf) {
#pragma unroll
    for (int j = 0; j < 4; j++) {
      int r = wave * 16 + j * 4 + g;
      int gb = (lane & 15) ^ (r & 7);
      gload_lds16(Kb + (size_t)(c * 64 + r) * 4096 + gb * 8,
                  &Ks[buf][(wave * 16 + j * 4) * 128]);
    }
  };

  f32x4 o[2][8] = {};
  float mrun[2] = {-1e30f, -1e30f};
  float lrun[2] = {0.f, 0.f};

  stage(0, 0);
  __syncthreads();
  int buf = 0;

  for (int c = 0; c < NCHUNK; c++) {
    if (c + 1 < NCHUNK) stage(c + 1, buf ^ 1);

    f32x4 acc[2][4] = {};
#pragma unroll
    for (int kv_t = 0; kv_t < 4; kv_t++) {
      int row = kv_t * 16 + fr;
#pragma unroll
      for (int kd = 0; kd < 4; kd++) {
        int pb = (kd * 4 + g) ^ (fr & 7);
        bf16x8 kf = *(const bf16x8*)&Ks[buf][row * 128 + pb * 8];
        acc[0][kv_t] = MFMA16(kf, qf[0][kd], acc[0][kv_t]);
        acc[1][kv_t] = MFMA16(kf, qf[1][kd], acc[1][kv_t]);
      }
    }

    bf16x8 vf0[8], vf1[8];
#pragma unroll
    for (int nn = 0; nn < 8; nn++) {
      const u16* vrow = Vt + (size_t)(nn * 16 + fr) * 1024 + c * 64 + fkb;
      vf0[nn] = *(const bf16x8*)(vrow);
      vf1[nn] = *(const bf16x8*)(vrow + 32);
    }

    float corr[2];
#pragma unroll
    for (int q_t = 0; q_t < 2; q_t++) {
      float pm = fmaxf(fmaxf(fmaxf(acc[q_t][0][0], acc[q_t][0][1]), fmaxf(acc[q_t][0][2], acc[q_t][0][3])),
                       fmaxf(fmaxf(acc[q_t][1][0], acc[q_t][1][1]), fmaxf(acc[q_t][1][2], acc[q_t][1][3])));
      pm = fmaxf(pm, fmaxf(fmaxf(fmaxf(acc[q_t][2][0], acc[q_t][2][1]), fmaxf(acc[q_t][2][2], acc[q_t][2][3])),
                           fmaxf(fmaxf(acc[q_t][3][0], acc[q_t][3][1]), fmaxf(acc[q_t][3][2], acc[q_t][3][3]))));
      pm = fmaxf(pm, __shfl_xor(pm, 16));
      pm = fmaxf(pm, __shfl_xor(pm, 32));
      float mn = fmaxf(mrun[q_t], pm);
      corr[q_t] = __expf(mrun[q_t] - mn);
      mrun[q_t] = mn;
      float psum = 0.f;
#pragma unroll
      for (int kv_t = 0; kv_t < 4; kv_t++) {
        float p0 = __expf(acc[q_t][kv_t][0] - mn);
        float p1 = __expf(acc[q_t][kv_t][1] - mn);
        float p2 = __expf(acc[q_t][kv_t][2] - mn);
        float p3 = __expf(acc[q_t][kv_t][3] - mn);
        psum += (p0 + p1) + (p2 + p3);
        union { __hip_bfloat162 h; unsigned int u; } lo, hi;
        lo.h = __float22bfloat162_rn(make_float2(p0, p1));
        hi.h = __float22bfloat162_rn(make_float2(p2, p3));
        u32x2 wv = {lo.u, hi.u};
        *(u32x2*)&P[(q_t * 16 + fr) * 72 + kv_t * 16 + g * 4] = wv;
      }
      lrun[q_t] = lrun[q_t] * corr[q_t] + psum;
    }

    float corr_o[2][4];
#pragma unroll
    for (int gq = 0; gq < 2; gq++)
#pragma unroll
      for (int r = 0; r < 4; r++)
        corr_o[gq][r] = __shfl(corr[gq], g * 4 + r);
#pragma unroll
    for (int gq = 0; gq < 2; gq++)
#pragma unroll
      for (int nn = 0; nn < 8; nn++) {
        o[gq][nn][0] *= corr_o[gq][0]; o[gq][nn][1] *= corr_o[gq][1];
        o[gq][nn][2] *= corr_o[gq][2]; o[gq][nn][3] *= corr_o[gq][3];
      }

    asm volatile("s_waitcnt lgkmcnt(0)" ::: "memory");
    {
      bf16x8 pa0 = *(const bf16x8*)&P[fr * 72 + fkb];
      bf16x8 pa1 = *(const bf16x8*)&P[(16 + fr) * 72 + fkb];
#pragma unroll
      for (int nn = 0; nn < 8; nn++) {
        o[0][nn] = MFMA16(pa0, vf0[nn], o[0][nn]);
        o[1][nn] = MFMA16(pa1, vf0[nn], o[1][nn]);
      }
      pa0 = *(const bf16x8*)&P[fr * 72 + 32 + fkb];
      pa1 = *(const bf16x8*)&P[(16 + fr) * 72 + 32 + fkb];
#pragma unroll
      for (int nn = 0; nn < 8; nn++) {
        o[0][nn] = MFMA16(pa0, vf1[nn], o[0][nn]);
        o[1][nn] = MFMA16(pa1, vf1[nn], o[1][nn]);
      }
    }

    __syncthreads();
    buf ^= 1;
  }

#pragma unroll
  for (int q_t = 0; q_t < 2; q_t++) {
    float lt = lrun[q_t];
    lt += __shfl_xor(lt, 16);
    lt += __shfl_xor(lt, 32);
    lrun[q_t] = lt;
  }
#pragma unroll
  for (int gq = 0; gq < 2; gq++)
#pragma unroll
    for (int r = 0; r < 4; r++) {
      float lt = __shfl(lrun[gq], g * 4 + r);
      float inv = 1.0f / lt;
      int row = b * SQ + q0 + gq * 16 + g * 4 + r;
      u16* Or = O + (size_t)row * 2048 + h * 128;
#pragma unroll
      for (int nn = 0; nn < 8; nn++) Or[nn * 16 + fr] = f2bf(o[gq][nn][r] * inv);
    }
}

// ---------------- launch ----------------
extern "C" void kernel_launch(void* const* d_in, const int* in_sizes, int n_in,
                              void* d_out, int out_size, void* d_ws, size_t ws_size,
                              hipStream_t stream) {
  const float* image_embeds  = (const float*)d_in[0];  // [2,1024,2048]
  const float* hidden_states = (const float*)d_in[1];  // [2,2048,3072]
  const float* Wq   = (const float*)d_in[2];           // [3072,2048]
  const float* Wkv  = (const float*)d_in[3];           // [2048,4096]
  const float* Wout = (const float*)d_in[4];           // [2048,3072]
  const float* ln1_g = (const float*)d_in[5];
  const float* ln1_b = (const float*)d_in[6];
  const float* ln2_g = (const float*)d_in[7];
  const float* ln2_b = (const float*)d_in[8];
  float* out = (float*)d_out;

  char* ws = (char*)d_ws;
  size_t off = 0;
  auto alloc = [&](size_t bytes) {
    void* p = ws + off;
    off += (bytes + 255) & ~(size_t)255;
    return p;
  };
  u16* Xq   = (u16*)alloc((size_t)4096 * 3072 * 2);  // LN(hidden) bf16; reused as AO
  u16* Xkv  = (u16*)alloc((size_t)2048 * 2048 * 2);  // LN(image) bf16
  u16* WqT  = (u16*)alloc((size_t)2048 * 3072 * 2);  // Wq^T bf16; reused as VT
  u16* WkvT = (u16*)alloc((size_t)4096 * 2048 * 2);  // Wkv^T bf16
  u16* WoT  = (u16*)alloc((size_t)3072 * 2048 * 2);  // Wout^T bf16
  u16* Qb   = (u16*)alloc((size_t)4096 * 2048 * 2);  // q bf16 (pre-scaled)
  u16* KVb  = (u16*)alloc((size_t)2048 * 4096 * 2);  // kv bf16
  u16* VTb  = WqT;   // alias: WqT dead after q-gemm
  u16* AO   = Xq;    // alias: Xq dead after q-gemm

  const float qscale = 0.08838834764831845f;  // 1/sqrt(128)

  ln_cast<3><<<4096, 256, 0, stream>>>(hidden_states, ln2_g, ln2_b, Xq, 3072);
  ln_cast<2><<<2048, 256, 0, stream>>>(image_embeds, ln1_g, ln1_b, Xkv, 2048);
  transpose_cast<<<dim3(2048 / 32, 3072 / 32), 256, 0, stream>>>(Wq, WqT, 3072, 2048);
  transpose_cast<<<dim3(4096 / 32, 2048 / 32), 256, 0, stream>>>(Wkv, WkvT, 2048, 4096);
  transpose_cast<<<dim3(3072 / 32, 2048 / 32), 256, 0, stream>>>(Wout, WoT, 2048, 3072);

  // combined q (128 tiles: 16x8) + kv (128 tiles: 8x16) -> 256 blocks, full fill
  gemm8<u16><<<256, 512, 0, stream>>>(
      Xq, WqT, Qb, 2048, 3072, qscale,
      Xkv, WkvT, KVb, 4096, 2048, 1.0f, 128);

  build_vt<<<dim3(4, 32, 32), 256, 0, stream>>>(KVb, VTb);
  attn_kernel<<<512, 256, 0, stream>>>(Qb, KVb, VTb, AO);

  // out: 4096x3072 -> 16x12 = 192 blocks
  gemm8<float><<<192, 512, 0, stream>>>(
      AO, WoT, out, 3072, 2048, 1.0f,
      AO, WoT, out, 3072, 2048, 1.0f, 192);
}